// Round 1
// baseline (391.328 us; speedup 1.0000x reference)
//
#include <hip/hip_runtime.h>
#include <cstdint>
#include <cstddef>

#define NN 100000
#define NE 1600000

typedef __attribute__((ext_vector_type(8))) short bf16x8;
typedef __attribute__((ext_vector_type(4))) short bf16x4;
typedef __attribute__((ext_vector_type(4))) float f32x4;

__device__ __forceinline__ short f2bf(float f) {
  uint32_t u = __builtin_bit_cast(uint32_t, f);
  u += 0x7FFFu + ((u >> 16) & 1u);   // RNE
  return (short)(u >> 16);
}

__device__ __forceinline__ float lrelu(float x) { return fmaxf(x, 0.1f * x); }

__device__ __forceinline__ void atomic_add_f32(float* p, float v) {
  __hip_atomic_fetch_add(p, v, __ATOMIC_RELAXED, __HIP_MEMORY_SCOPE_AGENT);
}

// Pre-transpose + bf16-convert all weights into ws:
//   W1t  [64][96]   (mW1^T)   offset 0
//   W2t  [64][64]   (mW2^T)   offset 6144
//   uW1t [64][128]  (uW1^T)   offset 10240
//   uW2t [64][64]   (uW2^T)   offset 18432
__global__ void prep_kernel(const float* __restrict__ W1, const float* __restrict__ W2,
                            const float* __restrict__ uW1, const float* __restrict__ uW2,
                            short* __restrict__ ws) {
  int t = blockIdx.x * 256 + threadIdx.x;
  const int n1 = 64 * 96, n2 = 64 * 64, n3 = 64 * 128, n4 = 64 * 64;
  if (t < n1) { int c = t / 96, k = t % 96; ws[t] = f2bf(W1[k * 64 + c]); return; }
  t -= n1;
  if (t < n2) { int c = t / 64, k = t % 64; ws[n1 + t] = f2bf(W2[k * 64 + c]); return; }
  t -= n2;
  if (t < n3) { int c = t / 128, k = t % 128; ws[n1 + n2 + t] = f2bf(uW1[k * 64 + c]); return; }
  t -= n3;
  if (t < n4) { int c = t / 64, k = t % 64; ws[n1 + n2 + n3 + t] = f2bf(uW2[k * 64 + c]); return; }
}

// Edge phase: per wave, 64 edges.
// GEMM1 swapped: acc1 = (W1^T)(X^T)  -> H^T fragments (4 consecutive hidden per reg quad)
// LDS: H[edge][hid] bf16, rows 128B, 16B-chunk XOR swizzle by (edge&7)
// GEMM2 normal:  acc2 = H * W2 -> Msg[edge][dim]; *edge_weight, atomicAdd into agg rows.
__global__ __launch_bounds__(256) void edge_kernel(
    const float* __restrict__ nf, const int* __restrict__ ei,
    const float* __restrict__ ea, const float* __restrict__ ew,
    const short* __restrict__ W1t, const float* __restrict__ b1,
    const short* __restrict__ W2t, const float* __restrict__ b2,
    float* __restrict__ agg) {
  __shared__ uint4 hbuf_s[4][512];  // 8KB per wave
  const int tid = threadIdx.x;
  const int wv = tid >> 6, ln = tid & 63;
  const int c = ln & 15, g = ln >> 4;
  char* hb = (char*)hbuf_s[wv];
  const long base = ((long)blockIdx.x * 4 + wv) * 64;

  int eid[4], srcn[4];
#pragma unroll
  for (int n = 0; n < 4; ++n) {
    eid[n] = (int)base + 16 * n + c;
    srcn[n] = ei[eid[n]];
  }

  f32x4 acc1[4][4];
#pragma unroll
  for (int i = 0; i < 4; ++i)
#pragma unroll
    for (int j = 0; j < 4; ++j) acc1[i][j] = f32x4{0.f, 0.f, 0.f, 0.f};

#pragma unroll
  for (int ks = 0; ks < 3; ++ks) {
    bf16x8 xf[4];
#pragma unroll
    for (int n = 0; n < 4; ++n) {
      const float* p = (ks < 2) ? (nf + (size_t)srcn[n] * 64 + ks * 32 + g * 8)
                                : (ea + (size_t)eid[n] * 32 + g * 8);
      float4 u = *(const float4*)p;
      float4 v = *(const float4*)(p + 4);
      bf16x8 t;
      t[0] = f2bf(u.x); t[1] = f2bf(u.y); t[2] = f2bf(u.z); t[3] = f2bf(u.w);
      t[4] = f2bf(v.x); t[5] = f2bf(v.y); t[6] = f2bf(v.z); t[7] = f2bf(v.w);
      xf[n] = t;
    }
#pragma unroll
    for (int m = 0; m < 4; ++m) {
      bf16x8 wf = *(const bf16x8*)(W1t + (size_t)(16 * m + c) * 96 + ks * 32 + g * 8);
#pragma unroll
      for (int n = 0; n < 4; ++n)
        acc1[m][n] = __builtin_amdgcn_mfma_f32_16x16x32_bf16(wf, xf[n], acc1[m][n], 0, 0, 0);
    }
  }

  // bias + leaky + transposed store H[edge][hid] (XOR-swizzled)
  float b1v[4][4];
#pragma unroll
  for (int m = 0; m < 4; ++m)
#pragma unroll
    for (int r = 0; r < 4; ++r) b1v[m][r] = b1[16 * m + 4 * g + r];

#pragma unroll
  for (int m = 0; m < 4; ++m) {
    const int h0 = 16 * m + 4 * g;
#pragma unroll
    for (int n = 0; n < 4; ++n) {
      const int e = 16 * n + c;
      bf16x4 pk;
#pragma unroll
      for (int r = 0; r < 4; ++r) pk[r] = f2bf(lrelu(acc1[m][n][r] + b1v[m][r]));
      const int byte = e * 128 + ((h0 * 2) ^ ((e & 7) << 4));
      *(bf16x4*)(hb + byte) = pk;
    }
  }
  // wave-private LDS buffer: in-wave lgkmcnt ordering suffices (no barrier)

  f32x4 acc2[4][4];
#pragma unroll
  for (int i = 0; i < 4; ++i)
#pragma unroll
    for (int j = 0; j < 4; ++j) acc2[i][j] = f32x4{0.f, 0.f, 0.f, 0.f};

#pragma unroll
  for (int ks = 0; ks < 2; ++ks) {
    bf16x8 hf[4];
#pragma unroll
    for (int m = 0; m < 4; ++m) {
      const int e = 16 * m + c;
      const int byte = e * 128 + ((ks * 64 + g * 16) ^ ((e & 7) << 4));
      hf[m] = *(const bf16x8*)(hb + byte);
    }
#pragma unroll
    for (int n = 0; n < 4; ++n) {
      bf16x8 wf = *(const bf16x8*)(W2t + (size_t)(16 * n + c) * 64 + ks * 32 + g * 8);
#pragma unroll
      for (int m = 0; m < 4; ++m)
        acc2[m][n] = __builtin_amdgcn_mfma_f32_16x16x32_bf16(hf[m], wf, acc2[m][n], 0, 0, 0);
    }
  }

  float b2v[4];
#pragma unroll
  for (int n = 0; n < 4; ++n) b2v[n] = b2[16 * n + c];

#pragma unroll
  for (int m = 0; m < 4; ++m) {
#pragma unroll
    for (int r = 0; r < 4; ++r) {
      const long e = base + 16 * m + 4 * g + r;
      const float w = ew[e];
      const int dst = ei[NE + e];
      float* ab = agg + (size_t)dst * 64 + c;
#pragma unroll
      for (int n = 0; n < 4; ++n)
        atomic_add_f32(ab + 16 * n, (acc2[m][n][r] + b2v[n]) * w);
    }
  }
}

// Node phase: per wave, 64 nodes. combined = [nf | agg] (agg lives in io).
// GEMM1 swapped -> z^T frags; +bias, LayerNorm (shfl_xor 16/32 across g-groups),
// leaky, transposed LDS store; GEMM2 normal -> out[node][dim] (overwrites io rows).
__global__ __launch_bounds__(256) void node_kernel(
    const float* __restrict__ nf,
    const short* __restrict__ W1t, const float* __restrict__ b1,
    const float* __restrict__ gam, const float* __restrict__ bet,
    const short* __restrict__ W2t, const float* __restrict__ b2,
    float* __restrict__ io) {
  __shared__ uint4 hbuf_s[4][512];
  const int tid = threadIdx.x;
  const int wv = tid >> 6, ln = tid & 63;
  const int c = ln & 15, g = ln >> 4;
  char* hb = (char*)hbuf_s[wv];
  const long base = ((long)blockIdx.x * 4 + wv) * 64;

  int nid[4];
#pragma unroll
  for (int n = 0; n < 4; ++n) {
    long r = base + 16 * n + c;
    nid[n] = (r < NN) ? (int)r : (NN - 1);
  }

  f32x4 acc1[4][4];
#pragma unroll
  for (int i = 0; i < 4; ++i)
#pragma unroll
    for (int j = 0; j < 4; ++j) acc1[i][j] = f32x4{0.f, 0.f, 0.f, 0.f};

#pragma unroll
  for (int ks = 0; ks < 4; ++ks) {
    bf16x8 xf[4];
#pragma unroll
    for (int n = 0; n < 4; ++n) {
      const float* p = (ks < 2) ? (nf + (size_t)nid[n] * 64 + ks * 32 + g * 8)
                                : (io + (size_t)nid[n] * 64 + (ks - 2) * 32 + g * 8);
      float4 u = *(const float4*)p;
      float4 v = *(const float4*)(p + 4);
      bf16x8 t;
      t[0] = f2bf(u.x); t[1] = f2bf(u.y); t[2] = f2bf(u.z); t[3] = f2bf(u.w);
      t[4] = f2bf(v.x); t[5] = f2bf(v.y); t[6] = f2bf(v.z); t[7] = f2bf(v.w);
      xf[n] = t;
    }
#pragma unroll
    for (int m = 0; m < 4; ++m) {
      bf16x8 wf = *(const bf16x8*)(W1t + (size_t)(16 * m + c) * 128 + ks * 32 + g * 8);
#pragma unroll
      for (int n = 0; n < 4; ++n)
        acc1[m][n] = __builtin_amdgcn_mfma_f32_16x16x32_bf16(wf, xf[n], acc1[m][n], 0, 0, 0);
    }
  }

  float b1v[4][4], gv[4][4], bv[4][4];
#pragma unroll
  for (int m = 0; m < 4; ++m)
#pragma unroll
    for (int r = 0; r < 4; ++r) {
      int h = 16 * m + 4 * g + r;
      b1v[m][r] = b1[h]; gv[m][r] = gam[h]; bv[m][r] = bet[h];
    }

#pragma unroll
  for (int n = 0; n < 4; ++n) {
    float s = 0.f;
#pragma unroll
    for (int m = 0; m < 4; ++m)
#pragma unroll
      for (int r = 0; r < 4; ++r) { acc1[m][n][r] += b1v[m][r]; s += acc1[m][n][r]; }
    s += __shfl_xor(s, 16);
    s += __shfl_xor(s, 32);
    const float mu = s * 0.015625f;
    float vs = 0.f;
#pragma unroll
    for (int m = 0; m < 4; ++m)
#pragma unroll
      for (int r = 0; r < 4; ++r) { float d = acc1[m][n][r] - mu; vs += d * d; }
    vs += __shfl_xor(vs, 16);
    vs += __shfl_xor(vs, 32);
    const float rstd = rsqrtf(vs * 0.015625f + 1e-5f);
    const int e = 16 * n + c;
#pragma unroll
    for (int m = 0; m < 4; ++m) {
      bf16x4 pk;
#pragma unroll
      for (int r = 0; r < 4; ++r)
        pk[r] = f2bf(lrelu((acc1[m][n][r] - mu) * rstd * gv[m][r] + bv[m][r]));
      const int byte = e * 128 + (((16 * m + 4 * g) * 2) ^ ((e & 7) << 4));
      *(bf16x4*)(hb + byte) = pk;
    }
  }

  f32x4 acc2[4][4];
#pragma unroll
  for (int i = 0; i < 4; ++i)
#pragma unroll
    for (int j = 0; j < 4; ++j) acc2[i][j] = f32x4{0.f, 0.f, 0.f, 0.f};

#pragma unroll
  for (int ks = 0; ks < 2; ++ks) {
    bf16x8 hf[4];
#pragma unroll
    for (int m = 0; m < 4; ++m) {
      const int e = 16 * m + c;
      const int byte = e * 128 + ((ks * 64 + g * 16) ^ ((e & 7) << 4));
      hf[m] = *(const bf16x8*)(hb + byte);
    }
#pragma unroll
    for (int n = 0; n < 4; ++n) {
      bf16x8 wf = *(const bf16x8*)(W2t + (size_t)(16 * n + c) * 64 + ks * 32 + g * 8);
#pragma unroll
      for (int m = 0; m < 4; ++m)
        acc2[m][n] = __builtin_amdgcn_mfma_f32_16x16x32_bf16(hf[m], wf, acc2[m][n], 0, 0, 0);
    }
  }

  float b2v[4];
#pragma unroll
  for (int n = 0; n < 4; ++n) b2v[n] = b2[16 * n + c];

#pragma unroll
  for (int m = 0; m < 4; ++m)
#pragma unroll
    for (int r = 0; r < 4; ++r) {
      const long node = base + 16 * m + 4 * g + r;
      if (node < NN) {
        float* op = io + (size_t)node * 64 + c;
#pragma unroll
        for (int n = 0; n < 4; ++n) op[16 * n] = acc2[m][n][r] + b2v[n];
      }
    }
}

extern "C" void kernel_launch(void* const* d_in, const int* in_sizes, int n_in,
                              void* d_out, int out_size, void* d_ws, size_t ws_size,
                              hipStream_t stream) {
  const float* nf  = (const float*)d_in[0];
  const int*   ei  = (const int*)d_in[1];
  const float* ea  = (const float*)d_in[2];
  const float* ew  = (const float*)d_in[3];
  const float* mW1 = (const float*)d_in[4];
  const float* mb1 = (const float*)d_in[5];
  const float* mW2 = (const float*)d_in[6];
  const float* mb2 = (const float*)d_in[7];
  const float* uW1 = (const float*)d_in[8];
  const float* ub1 = (const float*)d_in[9];
  const float* lng = (const float*)d_in[10];
  const float* lnb = (const float*)d_in[11];
  const float* uW2 = (const float*)d_in[12];
  const float* ub2 = (const float*)d_in[13];
  float* io = (float*)d_out;
  short* wsw = (short*)d_ws;

  hipMemsetAsync(d_out, 0, (size_t)NN * 64 * sizeof(float), stream);
  prep_kernel<<<88, 256, 0, stream>>>(mW1, mW2, uW1, uW2, wsw);

  const short* W1t  = wsw;
  const short* W2t  = wsw + 64 * 96;
  const short* uW1t = wsw + 64 * 96 + 64 * 64;
  const short* uW2t = uW1t + 64 * 128;

  edge_kernel<<<NE / 256, 256, 0, stream>>>(nf, ei, ea, ew, W1t, mb1, W2t, mb2, io);
  node_kernel<<<(NN + 255) / 256, 256, 0, stream>>>(nf, uW1t, ub1, lng, lnb, uW2t, ub2, io);
}